// Round 2
// baseline (366.664 us; speedup 1.0000x reference)
//
#include <hip/hip_runtime.h>

typedef int v4i  __attribute__((ext_vector_type(4)));
typedef int v16i __attribute__((ext_vector_type(16)));

__device__ __forceinline__ int pack4i(int a, int b, int c, int d) {
  return (a & 255) | ((b & 255) << 8) | ((c & 255) << 16) | ((d & 255) << 24);
}

// ---------------------------------------------------------------------------
// Pack (W + E) -> int8, transposed Bt[n][k] (row stride K bytes).
// Tile: 64 n x 256 k per block, 256 threads. Zero-pads n >= N rows.
// ---------------------------------------------------------------------------
__device__ void pack_tile(const int* __restrict__ W, const int* __restrict__ E,
                          char* __restrict__ Bt, int K, int N,
                          int nx, int ky, char* lin) {
  const int t = threadIdx.x;
  const int n0 = nx * 64, k0 = ky * 256;
  {
    const int kk = t >> 2, c = t & 3;
    for (int p = 0; p < 4; ++p) {
      const int k = kk + (p << 6);
      const long grow = (long)(k0 + k) * N;
      #pragma unroll
      for (int i = 0; i < 4; ++i) {
        const int nl = (c << 4) + (i << 2);
        const int ng = n0 + nl;
        int a0, a1, a2, a3;
        if (ng + 3 < N) {
          int4 wv = *(const int4*)(W + grow + ng);
          int4 ev = *(const int4*)(E + grow + ng);
          a0 = wv.x + ev.x; a1 = wv.y + ev.y; a2 = wv.z + ev.z; a3 = wv.w + ev.w;
        } else {
          a0 = (ng + 0 < N) ? W[grow + ng + 0] + E[grow + ng + 0] : 0;
          a1 = (ng + 1 < N) ? W[grow + ng + 1] + E[grow + ng + 1] : 0;
          a2 = (ng + 2 < N) ? W[grow + ng + 2] + E[grow + ng + 2] : 0;
          a3 = (ng + 3 < N) ? W[grow + ng + 3] + E[grow + ng + 3] : 0;
        }
        *(int*)(lin + k * 68 + nl) = pack4i(a0, a1, a2, a3);
      }
    }
  }
  __syncthreads();
  {
    const int n = t & 63, kq = t >> 6;
    char* dst = Bt + (long)(n0 + n) * K + k0 + (kq << 6);
    int outv[16];
    #pragma unroll
    for (int g = 0; g < 16; ++g) {
      const int k = (kq << 6) + (g << 2);
      outv[g] = pack4i(lin[(k + 0) * 68 + n], lin[(k + 1) * 68 + n],
                       lin[(k + 2) * 68 + n], lin[(k + 3) * 68 + n]);
    }
    #pragma unroll
    for (int g = 0; g < 4; ++g)
      *(int4*)(dst + (g << 4)) =
          make_int4(outv[g * 4], outv[g * 4 + 1], outv[g * 4 + 2], outv[g * 4 + 3]);
  }
}

__global__ __launch_bounds__(256) void pack_all_kernel(
    const int* W1, const int* E1, char* Bt1,
    const int* W2, const int* E2, char* Bt2,
    const int* W3, const int* E3, char* Bt3,
    const int* b1, const int* eb1, int* bs1,
    const int* b2, const int* eb2, int* bs2,
    const int* b3, const int* eb3, int* bs3) {
  __shared__ __align__(16) char lin[256 * 68];
  const int bid = blockIdx.x;
  if (bid < 192) {
    pack_tile(W1, E1, Bt1, 3072, 1024, bid % 16, bid / 16, lin);
  } else if (bid < 256) {
    const int l = bid - 192;
    pack_tile(W2, E2, Bt2, 1024, 1024, l % 16, l / 16, lin);
  } else if (bid < 264) {
    const int l = bid - 256;
    pack_tile(W3, E3, Bt3, 1024, 100, l & 1, l >> 1, lin);
  } else {
    const int t = threadIdx.x;
    for (int i = t; i < 1024; i += 256) {
      bs1[i] = b1[i] + eb1[i];
      bs2[i] = b2[i] + eb2[i];
    }
    for (int i = t; i < 128; i += 256)
      bs3[i] = (i < 100) ? (b3[i] + eb3[i]) : 0;
  }
}

// ---------------------------------------------------------------------------
// GEMM: C = trunc_i8(A @ Bt^T + bsum [+ H]) ; 128x128 tile, BK=64, 256 thr.
// AMODE 0: A is int32 [M][K]; AMODE 1: A is int8 [M][K].
// DO_HADD: add hiddens (int32, stride 1024) before truncation (layer 1).
// DO_I8OUT: write int8 result to A8out (stride 1024) via LDS transpose.
// DO_IOUT: write int32 result to Iout (stride ldC), masked to nvalid cols.
// ---------------------------------------------------------------------------
template<int AMODE, bool DO_HADD, bool DO_I8OUT, bool DO_IOUT, bool DO_MASK>
__global__ __launch_bounds__(256, 2) void gemm_kernel(
    const void* __restrict__ Asrc, const char* __restrict__ Btg,
    const int* __restrict__ bsum, const int* __restrict__ Hadd,
    char* __restrict__ A8out, int* __restrict__ Iout,
    const int K, const int ldC, const int nvalid) {
  __shared__ __align__(16) char smem[20480];
  char* As = smem;           // [128][80] int8, k-tile rows (16B aligned stride)
  char* Bs = smem + 10240;   // [128][80] int8, n rows of k bytes

  const int t = threadIdx.x;
  const int mt = blockIdx.x & 63;   // same-m blocks land on same XCD (bid%8 const)
  const int nt = blockIdx.x >> 6;
  const long m0 = (long)mt << 7;
  const int n0 = nt << 7;

  const int lane = t & 63, w = t >> 6;
  const int wm = w & 1, wn = w >> 1;
  const int lc = lane & 31, hg = lane >> 5;

  v16i acc[2][2] = {};

  const int sm = t >> 1, sh = t & 1;
  const long arow = (m0 + sm) * K + sh * 32;
  const char* Brow = Btg + (long)(n0 + sm) * K + sh * 32;
  char* AsW = As + sm * 80 + sh * 32;
  char* BsW = Bs + sm * 80 + sh * 32;

  const char* Ab = As + (wm * 64 + lc) * 80 + hg * 16;
  const char* Bb = Bs + (wn * 64 + lc) * 80 + hg * 16;

  const int kiters = K >> 6;
  for (int kt = 0; kt < kiters; ++kt) {
    const int kb = kt << 6;
    if (AMODE == 0) {
      const int* Ar = (const int*)Asrc + arow + kb;
      int d[8];
      #pragma unroll
      for (int i = 0; i < 8; ++i) {
        int4 v = *(const int4*)(Ar + (i << 2));
        d[i] = pack4i(v.x, v.y, v.z, v.w);
      }
      *(int4*)(AsW)      = make_int4(d[0], d[1], d[2], d[3]);
      *(int4*)(AsW + 16) = make_int4(d[4], d[5], d[6], d[7]);
    } else {
      const char* Ar = (const char*)Asrc + arow + kb;
      int4 v0 = *(const int4*)(Ar);
      int4 v1 = *(const int4*)(Ar + 16);
      *(int4*)(AsW)      = v0;
      *(int4*)(AsW + 16) = v1;
    }
    {
      int4 v0 = *(const int4*)(Brow + kb);
      int4 v1 = *(const int4*)(Brow + kb + 16);
      *(int4*)(BsW)      = v0;
      *(int4*)(BsW + 16) = v1;
    }
    __syncthreads();
    #pragma unroll
    for (int ks = 0; ks < 2; ++ks) {
      v4i a0 = *(const v4i*)(Ab + ks * 32);
      v4i a1 = *(const v4i*)(Ab + 32 * 80 + ks * 32);
      v4i b0 = *(const v4i*)(Bb + ks * 32);
      v4i b1 = *(const v4i*)(Bb + 32 * 80 + ks * 32);
      acc[0][0] = __builtin_amdgcn_mfma_i32_32x32x32_i8(a0, b0, acc[0][0], 0, 0, 0);
      acc[0][1] = __builtin_amdgcn_mfma_i32_32x32x32_i8(a0, b1, acc[0][1], 0, 0, 0);
      acc[1][0] = __builtin_amdgcn_mfma_i32_32x32x32_i8(a1, b0, acc[1][0], 0, 0, 0);
      acc[1][1] = __builtin_amdgcn_mfma_i32_32x32x32_i8(a1, b1, acc[1][1], 0, 0, 0);
    }
    __syncthreads();
  }

  // Epilogue. C/D layout: col = lane&31, row = (reg&3) + 8*(reg>>2) + 4*hg.
  const int bsv[2] = { bsum[n0 + wn * 64 + lc], bsum[n0 + wn * 64 + 32 + lc] };
  #pragma unroll
  for (int tm = 0; tm < 2; ++tm) {
    #pragma unroll
    for (int tn = 0; tn < 2; ++tn) {
      const int gcl = wn * 64 + tn * 32 + lc;
      const long gc = n0 + gcl;
      #pragma unroll
      for (int r = 0; r < 16; ++r) {
        const int lrow = wm * 64 + tm * 32 + (hg << 2) + (r & 3) + ((r >> 2) << 3);
        const long gm = m0 + lrow;
        int v = acc[tm][tn][r] + bsv[tn];
        if (DO_HADD) v += Hadd[gm * 1024 + gc];
        const int b8 = (int)(signed char)v;   // mod-256 truncate, sign-extend
        if (DO_I8OUT) smem[lrow * 144 + gcl] = (char)b8;
        if (DO_IOUT) {
          if (!DO_MASK || gcl < nvalid)
            Iout[gm * ldC + gc] = b8;          // d_out read back as int32
        }
      }
    }
  }
  if (DO_I8OUT) {
    __syncthreads();
    const char* src = smem + sm * 144 + sh * 64;
    char* dst = A8out + ((m0 + sm) << 10) + n0 + sh * 64;
    #pragma unroll
    for (int g = 0; g < 4; ++g)
      *(int4*)(dst + (g << 4)) = *(const int4*)(src + (g << 4));
  }
}

// ---------------------------------------------------------------------------
// ws layout (12.7 MB total): Bt1 | Bt2 | Bt3 | bs1 | bs2 | bs3 | A2
// Layer 3 reads h2 (int32) straight from d_out -> no A3 buffer.
// ---------------------------------------------------------------------------
extern "C" void kernel_launch(void* const* d_in, const int* in_sizes, int n_in,
                              void* d_out, int out_size, void* d_ws, size_t ws_size,
                              hipStream_t stream) {
  (void)in_sizes; (void)n_in; (void)out_size; (void)ws_size;
  const int* W1  = (const int*)d_in[0];
  const int* b1  = (const int*)d_in[1];
  const int* W2  = (const int*)d_in[2];
  const int* b2  = (const int*)d_in[3];
  const int* W3  = (const int*)d_in[4];
  const int* b3  = (const int*)d_in[5];
  const int* E1  = (const int*)d_in[6];
  const int* eb1 = (const int*)d_in[7];
  const int* E2  = (const int*)d_in[8];
  const int* eb2 = (const int*)d_in[9];
  const int* E3  = (const int*)d_in[10];
  const int* eb3 = (const int*)d_in[11];
  const int* X   = (const int*)d_in[12];   // [8192][3072] int32
  const int* H   = (const int*)d_in[13];   // [8192][1024] int32
  int* out = (int*)d_out;                  // h2 [8192*1024] then out [8192*100]

  char* ws  = (char*)d_ws;
  char* Bt1 = ws;                          // 3,145,728
  char* Bt2 = Bt1 + 3145728;               // 1,048,576
  char* Bt3 = Bt2 + 1048576;               //   131,072 (rows 100..127 zeroed)
  int*  bs1 = (int*)(Bt3 + 131072);        // 1024 ints
  int*  bs2 = bs1 + 1024;                  // 1024 ints
  int*  bs3 = bs2 + 1024;                  //  128 ints
  char* A2  = (char*)(bs3 + 128);          // 8,388,608 int8  (ends ~12.7 MB)

  pack_all_kernel<<<dim3(265), dim3(256), 0, stream>>>(
      W1, E1, Bt1, W2, E2, Bt2, W3, E3, Bt3,
      b1, eb1, bs1, b2, eb2, bs2, b3, eb3, bs3);

  // Layer 1: i2c fused with hiddens-add -> A2 (int8)
  gemm_kernel<0, true, true, false, false><<<dim3(512), dim3(256), 0, stream>>>(
      X, Bt1, bs1, H, A2, nullptr, 3072, 0, 1024);

  // Layer 2: h2 -> d_out (int32)
  gemm_kernel<1, false, false, true, false><<<dim3(512), dim3(256), 0, stream>>>(
      A2, Bt2, bs2, nullptr, nullptr, out, 1024, 1024, 1024);

  // Layer 3: reads h2 from d_out (int32), writes out region, 100 valid cols
  gemm_kernel<0, false, false, true, true><<<dim3(64), dim3(256), 0, stream>>>(
      out, Bt3, bs3, nullptr, nullptr, out + 8388608, 1024, 100, 100);
}